// Round 13
// baseline (121.443 us; speedup 1.0000x reference)
//
#include <hip/hip_runtime.h>
#include <hip/hip_bf16.h>

// HetConv via bf16 MFMA implicit GEMM, v13 = A/B isolation round.
// 2x2 completion: r9 (pad40 xs + padded wgts) = 100.6us; r12 (pad36 xs + frag-major
// wgts) = 107.5us. v13 = pad40 xs (single ds_read_b128 per fragment -- r12's b64
// split doubled xs-read issues, prime regression suspect) + frag-major weights
// (r12-proven: weight bank conflicts -> 0, fewer staging writes).
// Structure/sync/mapping/epilogue = r9/r12 verbatim: 1024 blocks, 256 thr (4 waves),
// M=256 x 128 px, 8 K-chunks, 4 __syncthreads per chunk, loads hoisted one phase.

#define IN_C  256
#define OUT_C 256
#define HH    64
#define WW    64

typedef __attribute__((ext_vector_type(8))) short bf16x8;
typedef __attribute__((ext_vector_type(4))) float f32x4;

__device__ __forceinline__ unsigned short f2bf(float f) {
    union { float f; unsigned int u; } v; v.f = f;
    unsigned int r = (v.u + 0x7FFFu + ((v.u >> 16) & 1u)) >> 16;
    return (unsigned short)r;
}

__device__ __forceinline__ unsigned pkbf(float lo, float hi) {
    union { __hip_bfloat162 b; unsigned u; } c;
    c.b = __float22bfloat162_rn(make_float2(lo, hi));
    return c.u;
}

// ---------------- weight prepass (fragment-major; r8/r10/r11/r12-proven) ----------------
// WH: [ck(8)][m(16)][lane(64)][e(8)]                                  = 65536 el
// WK: 65536 + [ck(8)][half(2)][tp(4)][bi(2)][mrow(2)][lane(64)][e(8)] = 131072 el
// decode: lrow=lane&15, kc=lane>>4; p=m*16+lrow; i=kc*8+e; g=ck&3, h2=ck>>2;
//         j=g+4*(32*h2+i); lo=bi*32+mrow*16+lrow; tf=half*4+tp; tfull=tf<4?tf:tf+1
__global__ __launch_bounds__(256)
void hetconv_prep(const float* __restrict__ Wk, const float* __restrict__ W1,
                  unsigned short* __restrict__ ws16) {
    const int TOTAL = 65536 + 131072;
    for (int idx = blockIdx.x * 256 + threadIdx.x; idx < TOTAL; idx += gridDim.x * 256) {
        float f;
        if (idx < 65536) {
            int e = idx & 7, lane = (idx >> 3) & 63, m = (idx >> 9) & 15, ck = idx >> 13;
            int g = ck & 3, h2 = ck >> 2;
            int p = m * 16 + (lane & 15);
            int i = (lane >> 4) * 8 + e;
            int j = g + 4 * (32 * h2 + i);
            int oc = 4 * (p & 63) + (p >> 6);
            f = ((p >> 6) == g) ? Wk[(oc * IN_C + j) * 9 + 4] : W1[oc * IN_C + j];
        } else {
            int k2 = idx - 65536;
            int e = k2 & 7, lane = (k2 >> 3) & 63;
            int mrow = (k2 >> 9) & 1, bi = (k2 >> 10) & 1, tp = (k2 >> 11) & 3;
            int hf = (k2 >> 13) & 1, ck = k2 >> 14;
            int g = ck & 3, h2 = ck >> 2;
            int tf = hf * 4 + tp, tfull = tf < 4 ? tf : tf + 1;
            int lo = bi * 32 + mrow * 16 + (lane & 15);
            int i = (lane >> 4) * 8 + e;
            int oc = 4 * lo + g;
            int j = g + 4 * (32 * h2 + i);
            f = Wk[(oc * IN_C + j) * 9 + tfull];
        }
        ws16[idx] = f2bf(f);
    }
}

// ---------------- main kernel helpers ----------------
#define XSPAD 40
#define XSSZ  (4 * 66 * XSPAD)   // 10560 el (21120 B)

// x chunk: 32 ic x 4 rows x 64 cols. tasks [r(4)][q(16)][icp(16)] = 1024 = 256*4
__device__ __forceinline__ void stage_x_loads(const float* __restrict__ x, int n, int y0,
                                              int ck, int t, float4 v[4][2]) {
    const int g = ck & 3, h2 = ck >> 2;
    #pragma unroll
    for (int it = 0; it < 4; ++it) {
        int tau = t + it * 256;
        int icp = tau & 15, q = (tau >> 4) & 15, r = tau >> 8;
        int i0 = icp * 2;
        int j0 = g + 4 * (32 * h2 + i0);
        int gy = y0 + r - 1;
        float4 z = {0.f, 0.f, 0.f, 0.f};
        v[it][0] = z; v[it][1] = z;
        if ((unsigned)gy < 64u) {
            const float* p0 = x + (((size_t)n * IN_C + j0) << 12) + (gy << 6) + (q << 2);
            v[it][0] = *(const float4*)p0;
            v[it][1] = *(const float4*)(p0 + 16384);   // plane j0+4 (K elem i0+1)
        }
    }
}

__device__ __forceinline__ void stage_x_writes(int t, float4 v[4][2], unsigned short* __restrict__ xb) {
    #pragma unroll
    for (int it = 0; it < 4; ++it) {
        int tau = t + it * 256;
        int icp = tau & 15, q = (tau >> 4) & 15, r = tau >> 8;
        int i0 = icp * 2;
        unsigned d0 = pkbf(v[it][0].x, v[it][1].x);
        unsigned d1 = pkbf(v[it][0].y, v[it][1].y);
        unsigned d2 = pkbf(v[it][0].z, v[it][1].z);
        unsigned d3 = pkbf(v[it][0].w, v[it][1].w);
        int rb = (r * 66 + q * 4 + 1) * XSPAD + i0;
        *(unsigned*)&xb[rb]             = d0;
        *(unsigned*)&xb[rb + XSPAD]     = d1;
        *(unsigned*)&xb[rb + 2 * XSPAD] = d2;
        *(unsigned*)&xb[rb + 3 * XSPAD] = d3;
    }
}

__device__ __forceinline__ f32x4 mfma(bf16x8 a, bf16x8 b, f32x4 c) {
    return __builtin_amdgcn_mfma_f32_16x16x32_bf16(a, b, c, 0, 0, 0);
}

// Part A: dense pointwise; wh frag-major (lane-linear b128, conflict-free);
// xs reads: single b128 (pad40 rows, 16B-aligned at el offsets multiple of 8)
__device__ __forceinline__ void partA(const unsigned short* __restrict__ xb,
        const unsigned short* __restrict__ whs, f32x4 acc[8][4],
        int mrow, int ncol, int lrow, int kc, int l) {
    bf16x8 b[4];
    #pragma unroll
    for (int ni = 0; ni < 4; ++ni)
        b[ni] = *(const bf16x8*)&xb[((ncol + 1) * 66 + ni * 16 + lrow + 1) * XSPAD + kc * 8];
    #pragma unroll
    for (int mi = 0; mi < 8; ++mi) {
        bf16x8 a = *(const bf16x8*)&whs[(mrow + 2 * mi) * 512 + l * 8];
        #pragma unroll
        for (int ni = 0; ni < 4; ++ni)
            acc[mi][ni] = mfma(a, b[ni], acc[mi][ni]);
    }
}

// Part B tap-half; wk frag-major. bi=0 -> acc[2G], bi=1 -> acc[2G+1] (r8-proven).
template <int G, int HALF>
__device__ __forceinline__ void taps(const unsigned short* __restrict__ xb,
        const unsigned short* __restrict__ wks, f32x4 acc[8][4],
        int mrow, int ncol, int lrow, int kc, int l) {
    #pragma unroll
    for (int tp = 0; tp < 4; ++tp) {
        const int tfull = HALF ? tp + 5 : tp;
        const int dy = tfull / 3 - 1, dx = tfull % 3 - 1;
        bf16x8 a0 = *(const bf16x8*)&wks[((tp * 2 + 0) * 2 + mrow) * 512 + l * 8];
        bf16x8 a1 = *(const bf16x8*)&wks[((tp * 2 + 1) * 2 + mrow) * 512 + l * 8];
        #pragma unroll
        for (int ni = 0; ni < 4; ++ni) {
            bf16x8 bb = *(const bf16x8*)&xb[((ncol + 1 + dy) * 66 + ni * 16 + lrow + 1 + dx) * XSPAD + kc * 8];
            acc[2 * G + 0][ni] = mfma(a0, bb, acc[2 * G + 0][ni]);
            acc[2 * G + 1][ni] = mfma(a1, bb, acc[2 * G + 1][ni]);
        }
    }
}

// ---------------- main MFMA kernel (r9 structure verbatim) ----------------
// Block: 256 thr (4 waves, 2 mrow x 2 ncol). 256 oc x 128 px (2 rows x 64 cols).
// Per chunk: bar(1) -> load wh/wka + x-writes + wh/wka LDS writes -> bar(2)
//            -> load wkb + partA + taps03 -> bar(3) -> wkb LDS write +
//            x-loads(k+1) -> bar(4) -> taps47
__global__ __launch_bounds__(256, 2)
void hetconv_mfma(const float* __restrict__ x,
                  const unsigned short* __restrict__ wgt,
                  float* __restrict__ out) {
    __shared__ unsigned short xs [XSSZ];   // 21120 B  [r][c 0..65][ic pad40]
    __shared__ unsigned short whs[8192];   // 16384 B  frag-major [m][lane][e]
    __shared__ unsigned short wks[8192];   // 16384 B  one tap-half [tp][bi][mrow][lane][e]
                                           // total 53888 B -> 2 blocks/CU
    const int t    = threadIdx.x;
    const int l    = t & 63;
    const int w    = t >> 6;
    const int mrow = w & 1;
    const int ncol = w >> 1;
    const int lrow = l & 15;
    const int kc   = l >> 4;

    const int bid = blockIdx.x;                 // 1024 blocks (r2/r9-proven mapping)
    const int n   = (bid & 7) * 4 + (bid >> 8);
    const int y0  = ((bid >> 3) & 31) * 2;

    const unsigned short* WHg = wgt;
    const unsigned short* WKg = wgt + 65536;

    f32x4 acc[8][4];
    #pragma unroll
    for (int mi = 0; mi < 8; ++mi)
        #pragma unroll
        for (int ni = 0; ni < 4; ++ni) acc[mi][ni] = (f32x4){0.f, 0.f, 0.f, 0.f};

    // ---- prologue: zero halo cols (never re-written) + hoist chunk-0 x loads ----
    if (t < 128) {
        int r = t >> 5, side = (t >> 4) & 1, u = t & 15;
        *(unsigned*)&xs[(r * 66 + side * 65) * XSPAD + u * 2] = 0u;
    }
    float4 xv[4][2];
    stage_x_loads(x, n, y0, 0, t, xv);

    // ---- 8 chunks, 4 barriers each (r9 structure) ----
#define CHUNK(CK, LAST)                                                          \
    {                                                                            \
        __syncthreads();                    /* (1) taps47(prev) done with xs */  \
        bf16x8 wv[8];                                                            \
        _Pragma("unroll")                                                        \
        for (int it = 0; it < 4; ++it) {    /* wh + wka global loads */          \
            int e = (t + it * 256) * 8;                                          \
            wv[it]     = *(const bf16x8*)&WHg[(CK) * 8192 + e];                  \
            wv[4 + it] = *(const bf16x8*)&WKg[(CK) * 16384 + e];                 \
        }                                                                        \
        stage_x_writes(t, xv, xs);          /* cvt_pk + ds_write (covers wv) */  \
        _Pragma("unroll")                                                        \
        for (int it = 0; it < 4; ++it) {                                         \
            int e = (t + it * 256) * 8;                                          \
            *(bf16x8*)&whs[e] = wv[it];                                          \
            *(bf16x8*)&wks[e] = wv[4 + it];                                      \
        }                                                                        \
        __syncthreads();                    /* (2) xs, wh, wka ready */          \
        bf16x8 wvb[4];                                                           \
        _Pragma("unroll")                                                        \
        for (int it = 0; it < 4; ++it)      /* wkb loads (overlap compute) */    \
            wvb[it] = *(const bf16x8*)&WKg[(CK) * 16384 + 8192 + (t + it * 256) * 8]; \
        partA(xs, whs, acc, mrow, ncol, lrow, kc, l);                            \
        taps<(CK) & 3, 0>(xs, wks, acc, mrow, ncol, lrow, kc, l);                \
        __syncthreads();                    /* (3) wka reads done */             \
        _Pragma("unroll")                                                        \
        for (int it = 0; it < 4; ++it)                                           \
            *(bf16x8*)&wks[(t + it * 256) * 8] = wvb[it];                        \
        if (!(LAST)) stage_x_loads(x, n, y0, (CK) + 1, t, xv);                   \
        __syncthreads();                    /* (4) wkb ready */                  \
        taps<(CK) & 3, 1>(xs, wks, acc, mrow, ncol, lrow, kc, l);                \
    }

    CHUNK(0, 0) CHUNK(1, 0) CHUNK(2, 0) CHUNK(3, 0)
    CHUNK(4, 0) CHUNK(5, 0) CHUNK(6, 0) CHUNK(7, 1)
#undef CHUNK

    // ---- epilogue: C/D layout col=lane&15, row=(lane>>4)*4+reg ----
    #pragma unroll
    for (int mi = 0; mi < 8; ++mi) {
        int m = mrow + 2 * mi;
        #pragma unroll
        for (int ni = 0; ni < 4; ++ni) {
            #pragma unroll
            for (int reg = 0; reg < 4; ++reg) {
                int p  = m * 16 + kc * 4 + reg;
                int oc = 4 * (p & 63) + (p >> 6);
                out[(((size_t)n * OUT_C + oc) * HH + (y0 + ncol)) * WW + ni * 16 + lrow] = acc[mi][ni][reg];
            }
        }
    }
}

// ---------------- fp32 fallback (only if ws too small) ----------------
#define TH 16
#define TW 16
#define ICC 16
__global__ __launch_bounds__(256)
void hetconv_fp32(const float* __restrict__ x,
                  const float* __restrict__ Wk,
                  const float* __restrict__ W1,
                  float* __restrict__ out) {
    const int t    = threadIdx.x;
    const int g    = blockIdx.y;
    const int n    = blockIdx.z;
    const int tile = blockIdx.x;
    const int ty0  = (tile >> 2) * TH;
    const int tx0  = (tile & 3) * TW;
    const int ol = t & 7;
    const int pl = t >> 3;
    const int r  = pl >> 1;
    const int ch = (pl & 1) * 8;
    __shared__ __align__(16) float xsf[ICC * 18 * 20];
    __shared__ __align__(16) float w1s[ICC * 64];
    __shared__ __align__(16) float wksf[4 * 9 * 64];
    float acc[8][8];
    #pragma unroll
    for (int k = 0; k < 8; ++k)
        #pragma unroll
        for (int p = 0; p < 8; ++p) acc[k][p] = 0.f;
    for (int ic0 = 0; ic0 < IN_C; ic0 += ICC) {
        for (int idx = t; idx < ICC * 18 * 18; idx += 256) {
            int ic = idx / 324, rem = idx - ic * 324, rr = rem / 18, cc = rem - rr * 18;
            int gy = ty0 + rr - 1, gx = tx0 + cc - 1;
            float v = 0.f;
            if (gy >= 0 && gy < HH && gx >= 0 && gx < WW)
                v = x[(((size_t)n * IN_C + ic0 + ic) * HH + gy) * WW + gx];
            xsf[ic * 360 + rr * 20 + cc] = v;
        }
        for (int idx = t; idx < ICC * 64; idx += 256) {
            int ic = idx >> 6, o = idx & 63;
            w1s[idx] = W1[(g + 4 * o) * IN_C + ic0 + ic];
        }
        for (int idx = t; idx < 4 * 9 * 64; idx += 256) {
            int a = idx / 576, rem = idx - a * 576, tap = rem >> 6, o = rem & 63;
            wksf[idx] = Wk[((g + 4 * o) * IN_C + ic0 + g + 4 * a) * 9 + tap];
        }
        __syncthreads();
        for (int ic = 0; ic < ICC; ++ic) {
            if ((ic & 3) != g) {
                const float* rowp = &xsf[ic * 360 + (r + 1) * 20 + ch];
                float4 A = *(const float4*)rowp;
                float4 B = *(const float4*)(rowp + 4);
                float  c8 = rowp[8];
                float xv2[8] = {A.y, A.z, A.w, B.x, B.y, B.z, B.w, c8};
                const float* wp = &w1s[ic * 64 + ol * 8];
                float4 wA = *(const float4*)wp;
                float4 wB = *(const float4*)(wp + 4);
                float wv2[8] = {wA.x, wA.y, wA.z, wA.w, wB.x, wB.y, wB.z, wB.w};
                #pragma unroll
                for (int k = 0; k < 8; ++k)
                    #pragma unroll
                    for (int p = 0; p < 8; ++p) acc[k][p] += wv2[k] * xv2[p];
            } else {
                const int a = ic >> 2;
                #pragma unroll
                for (int dy = -1; dy <= 1; ++dy) {
                    const float* rowp = &xsf[ic * 360 + (r + 1 + dy) * 20 + ch];
                    float4 A = *(const float4*)rowp;
                    float4 B = *(const float4*)(rowp + 4);
                    float2 C = *(const float2*)(rowp + 8);
                    float seg[10] = {A.x, A.y, A.z, A.w, B.x, B.y, B.z, B.w, C.x, C.y};
                    #pragma unroll
                    for (int dxi = 0; dxi < 3; ++dxi) {
                        const float* wp = &wksf[(a * 9 + (dy + 1) * 3 + dxi) * 64 + ol * 8];
                        float4 wA = *(const float4*)wp;
                        float4 wB = *(const float4*)(wp + 4);
                        float wv2[8] = {wA.x, wA.y, wA.z, wA.w, wB.x, wB.y, wB.z, wB.w};
                        #pragma unroll
                        for (int k = 0; k < 8; ++k)
                            #pragma unroll
                            for (int p = 0; p < 8; ++p) acc[k][p] += wv2[k] * seg[p + dxi];
                    }
                }
            }
        }
        __syncthreads();
    }
    #pragma unroll
    for (int k = 0; k < 8; ++k) {
        int oc = g + 4 * (ol * 8 + k);
        size_t base = (((size_t)n * OUT_C + oc) * HH + (ty0 + r)) * WW + tx0 + ch;
        float4 v0 = {acc[k][0], acc[k][1], acc[k][2], acc[k][3]};
        float4 v1 = {acc[k][4], acc[k][5], acc[k][6], acc[k][7]};
        *(float4*)(&out[base])     = v0;
        *(float4*)(&out[base + 4]) = v1;
    }
}

extern "C" void kernel_launch(void* const* d_in, const int* in_sizes, int n_in,
                              void* d_out, int out_size, void* d_ws, size_t ws_size,
                              hipStream_t stream) {
    const float* x  = (const float*)d_in[0];
    const float* Wk = (const float*)d_in[1];
    const float* W1 = (const float*)d_in[2];
    float* outp = (float*)d_out;

    if (ws_size >= (size_t)(65536 + 131072) * sizeof(unsigned short)) {
        hetconv_prep<<<256, 256, 0, stream>>>(Wk, W1, (unsigned short*)d_ws);
        hetconv_mfma<<<1024, 256, 0, stream>>>(x, (const unsigned short*)d_ws, outp);
    } else {
        hetconv_fp32<<<dim3(16, 4, 32), 256, 0, stream>>>(x, Wk, W1, outp);
    }
}

// Round 14
// 109.464 us; speedup vs baseline: 1.1094x; 1.1094x over previous
//
#include <hip/hip_runtime.h>
#include <hip/hip_bf16.h>

// HetConv via bf16 MFMA implicit GEMM, v14 = r9 VERBATIM (best: 100.6us) + exactly
// one variable: T5 s_setprio(1)/(0) around the two MFMA clusters.
// Rationale: 2 independent blocks/CU run at uncorrelated phases -> compute-phase
// waves can be prioritized over staging-phase waves (T5 mechanism needs role
// diversity; within-block waves are lockstep but cross-block they are not).
// Everything else -- prepass, layouts (pad-40), mapping, 4 barriers/chunk, hoisted
// loads, packed cvt -- is r9 byte-for-byte. 2x2 from r12/r13 proved all weight-
// layout changes poison L2 write-combining (WRITE 131->148->175MB); do not touch.

#define IN_C  256
#define OUT_C 256
#define HH    64
#define WW    64

typedef __attribute__((ext_vector_type(8))) short bf16x8;
typedef __attribute__((ext_vector_type(4))) float f32x4;

__device__ __forceinline__ unsigned short f2bf(float f) {
    union { float f; unsigned int u; } v; v.f = f;
    unsigned int r = (v.u + 0x7FFFu + ((v.u >> 16) & 1u)) >> 16;
    return (unsigned short)r;
}

__device__ __forceinline__ unsigned pkbf(float lo, float hi) {
    union { __hip_bfloat162 b; unsigned u; } c;
    c.b = __float22bfloat162_rn(make_float2(lo, hi));
    return c.u;
}

// ---------------- weight prepass (identical to r2/r9) ----------------
// What: [h=0..7][p=0..255][40]                      (h = h2*4+g ; j = g+4*(32*h2+i))
// Wkt : offset 81920: [h][tap=0..7][lo=0..63][40]   (tap_full = tap<4 ? tap : tap+1)
__global__ __launch_bounds__(256)
void hetconv_prep(const float* __restrict__ Wk, const float* __restrict__ W1,
                  unsigned short* __restrict__ ws16) {
    const int total = 81920 + 163840;
    for (int idx = blockIdx.x * 256 + threadIdx.x; idx < total; idx += gridDim.x * 256) {
        float f = 0.f;
        if (idx < 81920) {
            int i = idx % 40;
            int p = (idx / 40) & 255;
            int h = idx / 10240;
            int g = h & 3, h2 = h >> 2;
            if (i < 32) {
                int j  = g + 4 * (32 * h2 + i);
                int oc = 4 * (p & 63) + (p >> 6);
                f = ((p >> 6) == g) ? Wk[(oc * IN_C + j) * 9 + 4] : W1[oc * IN_C + j];
            }
        } else {
            int widx = idx - 81920;
            int i   = widx % 40;
            int lo  = (widx / 40) & 63;
            int tap = (widx / 2560) & 7;
            int h   = widx / 20480;
            int g = h & 3, h2 = h >> 2;
            if (i < 32) {
                int j  = g + 4 * (32 * h2 + i);
                int oc = 4 * lo + g;
                int tf = tap < 4 ? tap : tap + 1;
                f = Wk[(oc * IN_C + j) * 9 + tf];
            }
        }
        ws16[idx] = f2bf(f);
    }
}

// ---------------- main kernel helpers (r9 verbatim) ----------------
// x chunk: 32 ic x 4 rows x 64 cols. tasks [r(4)][q(16)][icp(16)] = 1024 = 256*4
__device__ __forceinline__ void stage_x_loads(const float* __restrict__ x, int n, int y0,
                                              int ck, int t, float4 v[4][2]) {
    const int g = ck & 3, h2 = ck >> 2;
    #pragma unroll
    for (int it = 0; it < 4; ++it) {
        int tau = t + it * 256;
        int icp = tau & 15, q = (tau >> 4) & 15, r = tau >> 8;
        int i0 = icp * 2;
        int j0 = g + 4 * (32 * h2 + i0);
        int gy = y0 + r - 1;
        float4 z = {0.f, 0.f, 0.f, 0.f};
        v[it][0] = z; v[it][1] = z;
        if ((unsigned)gy < 64u) {
            const float* p0 = x + (((size_t)n * IN_C + j0) << 12) + (gy << 6) + (q << 2);
            v[it][0] = *(const float4*)p0;
            v[it][1] = *(const float4*)(p0 + 16384);   // plane j0+4 (K elem i0+1)
        }
    }
}

__device__ __forceinline__ void stage_x_writes(int t, float4 v[4][2], unsigned short* __restrict__ xb) {
    #pragma unroll
    for (int it = 0; it < 4; ++it) {
        int tau = t + it * 256;
        int icp = tau & 15, q = (tau >> 4) & 15, r = tau >> 8;
        int i0 = icp * 2;
        unsigned d0 = pkbf(v[it][0].x, v[it][1].x);
        unsigned d1 = pkbf(v[it][0].y, v[it][1].y);
        unsigned d2 = pkbf(v[it][0].z, v[it][1].z);
        unsigned d3 = pkbf(v[it][0].w, v[it][1].w);
        int rb = (r * 66 + q * 4 + 1) * 40 + i0;
        *(unsigned*)&xb[rb]        = d0;
        *(unsigned*)&xb[rb + 40]   = d1;
        *(unsigned*)&xb[rb + 80]   = d2;
        *(unsigned*)&xb[rb + 120]  = d3;
    }
}

// ---------------- main MFMA kernel ----------------
// Block: 256 thr (4 waves, 2 mrow x 2 ncol). Computes all 256 oc x 128 px
// (2 output rows x 64 cols) for one (n, ytile). K-loop: 8 chunks of 32 ic.
__global__ __launch_bounds__(256, 2)
void hetconv_mfma(const float* __restrict__ x,
                  const unsigned short* __restrict__ wsw,
                  float* __restrict__ out) {
    __shared__ unsigned short xs[4 * 66 * 40];   // 21120 B  [r][c 0..65][ic pad40]
    __shared__ unsigned short wh[256 * 40];      // 20480 B  W_hat chunk [p][i pad40]
    __shared__ unsigned short wk[4 * 64 * 40];   // 20480 B  4 taps [tap][lo][i pad40]

    const int t    = threadIdx.x;
    const int l    = t & 63;
    const int w    = t >> 6;
    const int mrow = w & 1;
    const int ncol = w >> 1;
    const int lrow = l & 15;
    const int kc   = l >> 4;

    const int bid = blockIdx.x;                 // 1024 blocks (r2-proven mapping)
    const int n   = (bid & 7) * 4 + (bid >> 8);
    const int y0  = ((bid >> 3) & 31) * 2;

    f32x4 acc[8][4];
    #pragma unroll
    for (int mi = 0; mi < 8; ++mi)
        #pragma unroll
        for (int ni = 0; ni < 4; ++ni) acc[mi][ni] = (f32x4){0.f, 0.f, 0.f, 0.f};

    // ---- prologue: zero halo cols (never re-written) + hoist chunk-0 x loads ----
    if (t < 128) {
        int r = t >> 5, side = (t >> 4) & 1, u = t & 15;
        *(unsigned*)&xs[(r * 66 + side * 65) * 40 + u * 2] = 0u;
    }
    float4 xv[4][2];
    stage_x_loads(x, n, y0, 0, t, xv);

    // ---- 8 chunks, 4 barriers each (r9 structure), loads hoisted one phase ----
#define CHUNK(CK, LAST)                                                             \
    {                                                                               \
        const unsigned short* hs = wsw + (CK) * 10240;                              \
        const unsigned short* ks = wsw + 81920 + (CK) * 20480;                      \
        __syncthreads();                       /* (1) tapsB(prev) done with xs */   \
        bf16x8 wv[10];                                                              \
        _Pragma("unroll")                                                           \
        for (int it = 0; it < 5; ++it) {       /* wh+wka loads first (overlap) */   \
            int e = (t + it * 256) * 8;                                             \
            wv[it]     = *(const bf16x8*)&hs[e];                                    \
            wv[5 + it] = *(const bf16x8*)&ks[e];                                    \
        }                                                                           \
        stage_x_writes(t, xv, xs);             /* cvt_pk + ds_write (covers wv) */  \
        _Pragma("unroll")                                                           \
        for (int it = 0; it < 5; ++it) {                                            \
            int e = (t + it * 256) * 8;                                             \
            *(bf16x8*)&wh[e] = wv[it];                                              \
            *(bf16x8*)&wk[e] = wv[5 + it];                                          \
        }                                                                           \
        __syncthreads();                       /* (2) xs, wh, wka ready */          \
        bf16x8 wvb[5];                                                              \
        _Pragma("unroll")                                                           \
        for (int it = 0; it < 5; ++it)         /* wkb loads (overlap compute) */    \
            wvb[it] = *(const bf16x8*)&ks[10240 + (t + it * 256) * 8];              \
        __builtin_amdgcn_s_setprio(1);         /* T5: favor compute waves */        \
        {   /* part A: dense pointwise, K=32 */                                     \
            bf16x8 a[8], b[4];                                                      \
            _Pragma("unroll")                                                       \
            for (int mi = 0; mi < 8; ++mi) {                                        \
                int m = mrow + 2 * mi;                                              \
                a[mi] = *(const bf16x8*)&wh[(m * 16 + lrow) * 40 + kc * 8];         \
            }                                                                       \
            _Pragma("unroll")                                                       \
            for (int ni = 0; ni < 4; ++ni)                                          \
                b[ni] = *(const bf16x8*)&xs[((ncol + 1) * 66 + ni * 16 + lrow + 1) * 40 + kc * 8]; \
            _Pragma("unroll")                                                       \
            for (int mi = 0; mi < 8; ++mi)                                          \
                _Pragma("unroll")                                                   \
                for (int ni = 0; ni < 4; ++ni)                                      \
                    acc[mi][ni] = __builtin_amdgcn_mfma_f32_16x16x32_bf16(a[mi], b[ni], acc[mi][ni], 0, 0, 0); \
        }                                                                           \
        {   /* part B taps 0-3 (tap_full 0..3) */                                   \
            constexpr int G = (CK) & 3;                                             \
            _Pragma("unroll")                                                       \
            for (int tp = 0; tp < 4; ++tp) {                                        \
                const int dy = tp / 3 - 1, dx = tp % 3 - 1;                         \
                bf16x8 a0 = *(const bf16x8*)&wk[(tp * 64 + mrow * 16 + lrow) * 40 + kc * 8]; \
                bf16x8 a1 = *(const bf16x8*)&wk[(tp * 64 + (mrow + 2) * 16 + lrow) * 40 + kc * 8]; \
                _Pragma("unroll")                                                   \
                for (int ni = 0; ni < 4; ++ni) {                                    \
                    bf16x8 bb = *(const bf16x8*)&xs[((ncol + 1 + dy) * 66 + ni * 16 + lrow + 1 + dx) * 40 + kc * 8]; \
                    acc[2 * G + 0][ni] = __builtin_amdgcn_mfma_f32_16x16x32_bf16(a0, bb, acc[2 * G + 0][ni], 0, 0, 0); \
                    acc[2 * G + 1][ni] = __builtin_amdgcn_mfma_f32_16x16x32_bf16(a1, bb, acc[2 * G + 1][ni], 0, 0, 0); \
                }                                                                   \
            }                                                                       \
        }                                                                           \
        __builtin_amdgcn_s_setprio(0);                                              \
        __syncthreads();                       /* (3) wka reads done */             \
        _Pragma("unroll")                                                           \
        for (int it = 0; it < 5; ++it)                                              \
            *(bf16x8*)&wk[(t + it * 256) * 8] = wvb[it];                            \
        if (!(LAST)) stage_x_loads(x, n, y0, (CK) + 1, t, xv);  /* overlap tapsB */ \
        __syncthreads();                       /* (4) wkb ready */                  \
        __builtin_amdgcn_s_setprio(1);                                              \
        {   /* part B taps 4-7 (tap_full 5..8) */                                   \
            constexpr int G = (CK) & 3;                                             \
            _Pragma("unroll")                                                       \
            for (int tp = 0; tp < 4; ++tp) {                                        \
                const int tf = tp + 5;                                              \
                const int dy = tf / 3 - 1, dx = tf % 3 - 1;                         \
                bf16x8 a0 = *(const bf16x8*)&wk[(tp * 64 + mrow * 16 + lrow) * 40 + kc * 8]; \
                bf16x8 a1 = *(const bf16x8*)&wk[(tp * 64 + (mrow + 2) * 16 + lrow) * 40 + kc * 8]; \
                _Pragma("unroll")                                                   \
                for (int ni = 0; ni < 4; ++ni) {                                    \
                    bf16x8 bb = *(const bf16x8*)&xs[((ncol + 1 + dy) * 66 + ni * 16 + lrow + 1 + dx) * 40 + kc * 8]; \
                    acc[2 * G + 0][ni] = __builtin_amdgcn_mfma_f32_16x16x32_bf16(a0, bb, acc[2 * G + 0][ni], 0, 0, 0); \
                    acc[2 * G + 1][ni] = __builtin_amdgcn_mfma_f32_16x16x32_bf16(a1, bb, acc[2 * G + 1][ni], 0, 0, 0); \
                }                                                                   \
            }                                                                       \
        }                                                                           \
        __builtin_amdgcn_s_setprio(0);                                              \
    }

    CHUNK(0, 0) CHUNK(1, 0) CHUNK(2, 0) CHUNK(3, 0)
    CHUNK(4, 0) CHUNK(5, 0) CHUNK(6, 0) CHUNK(7, 1)
#undef CHUNK

    // ---- epilogue: C/D layout col=lane&15, row=(lane>>4)*4+reg ----
    #pragma unroll
    for (int mi = 0; mi < 8; ++mi) {
        int m = mrow + 2 * mi;
        #pragma unroll
        for (int ni = 0; ni < 4; ++ni) {
            #pragma unroll
            for (int reg = 0; reg < 4; ++reg) {
                int p  = m * 16 + kc * 4 + reg;
                int oc = 4 * (p & 63) + (p >> 6);
                out[(((size_t)n * OUT_C + oc) * HH + (y0 + ncol)) * WW + ni * 16 + lrow] = acc[mi][ni][reg];
            }
        }
    }
}

// ---------------- fp32 fallback (only if ws too small) ----------------
#define TH 16
#define TW 16
#define ICC 16
__global__ __launch_bounds__(256)
void hetconv_fp32(const float* __restrict__ x,
                  const float* __restrict__ Wk,
                  const float* __restrict__ W1,
                  float* __restrict__ out) {
    const int t    = threadIdx.x;
    const int g    = blockIdx.y;
    const int n    = blockIdx.z;
    const int tile = blockIdx.x;
    const int ty0  = (tile >> 2) * TH;
    const int tx0  = (tile & 3) * TW;
    const int ol = t & 7;
    const int pl = t >> 3;
    const int r  = pl >> 1;
    const int ch = (pl & 1) * 8;
    __shared__ __align__(16) float xsf[ICC * 18 * 20];
    __shared__ __align__(16) float w1s[ICC * 64];
    __shared__ __align__(16) float wksf[4 * 9 * 64];
    float acc[8][8];
    #pragma unroll
    for (int k = 0; k < 8; ++k)
        #pragma unroll
        for (int p = 0; p < 8; ++p) acc[k][p] = 0.f;
    for (int ic0 = 0; ic0 < IN_C; ic0 += ICC) {
        for (int idx = t; idx < ICC * 18 * 18; idx += 256) {
            int ic = idx / 324, rem = idx - ic * 324, rr = rem / 18, cc = rem - rr * 18;
            int gy = ty0 + rr - 1, gx = tx0 + cc - 1;
            float v = 0.f;
            if (gy >= 0 && gy < HH && gx >= 0 && gx < WW)
                v = x[(((size_t)n * IN_C + ic0 + ic) * HH + gy) * WW + gx];
            xsf[ic * 360 + rr * 20 + cc] = v;
        }
        for (int idx = t; idx < ICC * 64; idx += 256) {
            int ic = idx >> 6, o = idx & 63;
            w1s[idx] = W1[(g + 4 * o) * IN_C + ic0 + ic];
        }
        for (int idx = t; idx < 4 * 9 * 64; idx += 256) {
            int a = idx / 576, rem = idx - a * 576, tap = rem >> 6, o = rem & 63;
            wksf[idx] = Wk[((g + 4 * o) * IN_C + ic0 + g + 4 * a) * 9 + tap];
        }
        __syncthreads();
        for (int ic = 0; ic < ICC; ++ic) {
            if ((ic & 3) != g) {
                const float* rowp = &xsf[ic * 360 + (r + 1) * 20 + ch];
                float4 A = *(const float4*)rowp;
                float4 B = *(const float4*)(rowp + 4);
                float  c8 = rowp[8];
                float xv2[8] = {A.y, A.z, A.w, B.x, B.y, B.z, B.w, c8};
                const float* wp = &w1s[ic * 64 + ol * 8];
                float4 wA = *(const float4*)wp;
                float4 wB = *(const float4*)(wp + 4);
                float wv2[8] = {wA.x, wA.y, wA.z, wA.w, wB.x, wB.y, wB.z, wB.w};
                #pragma unroll
                for (int k = 0; k < 8; ++k)
                    #pragma unroll
                    for (int p = 0; p < 8; ++p) acc[k][p] += wv2[k] * xv2[p];
            } else {
                const int a = ic >> 2;
                #pragma unroll
                for (int dy = -1; dy <= 1; ++dy) {
                    const float* rowp = &xsf[ic * 360 + (r + 1 + dy) * 20 + ch];
                    float4 A = *(const float4*)rowp;
                    float4 B = *(const float4*)(rowp + 4);
                    float2 C = *(const float2*)(rowp + 8);
                    float seg[10] = {A.x, A.y, A.z, A.w, B.x, B.y, B.z, B.w, C.x, C.y};
                    #pragma unroll
                    for (int dxi = 0; dxi < 3; ++dxi) {
                        const float* wp = &wksf[(a * 9 + (dy + 1) * 3 + dxi) * 64 + ol * 8];
                        float4 wA = *(const float4*)wp;
                        float4 wB = *(const float4*)(wp + 4);
                        float wv2[8] = {wA.x, wA.y, wA.z, wA.w, wB.x, wB.y, wB.z, wB.w};
                        #pragma unroll
                        for (int k = 0; k < 8; ++k)
                            #pragma unroll
                            for (int p = 0; p < 8; ++p) acc[k][p] += wv2[k] * seg[p + dxi];
                    }
                }
            }
        }
        __syncthreads();
    }
    #pragma unroll
    for (int k = 0; k < 8; ++k) {
        int oc = g + 4 * (ol * 8 + k);
        size_t base = (((size_t)n * OUT_C + oc) * HH + (ty0 + r)) * WW + tx0 + ch;
        float4 v0 = {acc[k][0], acc[k][1], acc[k][2], acc[k][3]};
        float4 v1 = {acc[k][4], acc[k][5], acc[k][6], acc[k][7]};
        *(float4*)(&out[base])     = v0;
        *(float4*)(&out[base + 4]) = v1;
    }
}

extern "C" void kernel_launch(void* const* d_in, const int* in_sizes, int n_in,
                              void* d_out, int out_size, void* d_ws, size_t ws_size,
                              hipStream_t stream) {
    const float* x  = (const float*)d_in[0];
    const float* Wk = (const float*)d_in[1];
    const float* W1 = (const float*)d_in[2];
    float* outp = (float*)d_out;

    if (ws_size >= (size_t)(81920 + 163840) * sizeof(unsigned short)) {
        hetconv_prep<<<240, 256, 0, stream>>>(Wk, W1, (unsigned short*)d_ws);
        hetconv_mfma<<<1024, 256, 0, stream>>>(x, (const unsigned short*)d_ws, outp);
    } else {
        hetconv_fp32<<<dim3(16, 4, 32), 256, 0, stream>>>(x, Wk, W1, outp);
    }
}

// Round 15
// 101.742 us; speedup vs baseline: 1.1936x; 1.0759x over previous
//
#include <hip/hip_runtime.h>
#include <hip/hip_bf16.h>

// HetConv via bf16 MFMA implicit GEMM — FINAL = r9 verbatim (session best: 100.6us).
// Ladder: fp32 1123us -> bf16 MFMA 105us (r2) -> +packed cvt +one-phase load
// hoisting = 100.6us (r9). All structural escapes (global_load_lds DMA r5, M-split
// r7, 512-thr r4, counted-vmcnt r8) and isolated A/B probes on this base
// (frag-major weights r13: 121us; pad-36 xs r12: 107us; s_setprio r14: 109us)
// regressed — each perturbation of the global-load streams amplifies WRITE_SIZE
// (131 -> 148-390 MB), i.e. breaks L2 write-combining of the fp32 output.
// Residual gap (wall ~100us vs ~66us LDS-pipe busy) is phase serialization at
// register-capped occupancy (acc=128 AGPR + ~128 VGPR => 2 blocks/CU hard cap).

#define IN_C  256
#define OUT_C 256
#define HH    64
#define WW    64

typedef __attribute__((ext_vector_type(8))) short bf16x8;
typedef __attribute__((ext_vector_type(4))) float f32x4;

__device__ __forceinline__ unsigned short f2bf(float f) {
    union { float f; unsigned int u; } v; v.f = f;
    unsigned int r = (v.u + 0x7FFFu + ((v.u >> 16) & 1u)) >> 16;
    return (unsigned short)r;
}

__device__ __forceinline__ unsigned pkbf(float lo, float hi) {
    union { __hip_bfloat162 b; unsigned u; } c;
    c.b = __float22bfloat162_rn(make_float2(lo, hi));
    return c.u;
}

// ---------------- weight prepass ----------------
// What: [h=0..7][p=0..255][40]                      (h = h2*4+g ; j = g+4*(32*h2+i))
// Wkt : offset 81920: [h][tap=0..7][lo=0..63][40]   (tap_full = tap<4 ? tap : tap+1)
__global__ __launch_bounds__(256)
void hetconv_prep(const float* __restrict__ Wk, const float* __restrict__ W1,
                  unsigned short* __restrict__ ws16) {
    const int total = 81920 + 163840;
    for (int idx = blockIdx.x * 256 + threadIdx.x; idx < total; idx += gridDim.x * 256) {
        float f = 0.f;
        if (idx < 81920) {
            int i = idx % 40;
            int p = (idx / 40) & 255;
            int h = idx / 10240;
            int g = h & 3, h2 = h >> 2;
            if (i < 32) {
                int j  = g + 4 * (32 * h2 + i);
                int oc = 4 * (p & 63) + (p >> 6);
                f = ((p >> 6) == g) ? Wk[(oc * IN_C + j) * 9 + 4] : W1[oc * IN_C + j];
            }
        } else {
            int widx = idx - 81920;
            int i   = widx % 40;
            int lo  = (widx / 40) & 63;
            int tap = (widx / 2560) & 7;
            int h   = widx / 20480;
            int g = h & 3, h2 = h >> 2;
            if (i < 32) {
                int j  = g + 4 * (32 * h2 + i);
                int oc = 4 * lo + g;
                int tf = tap < 4 ? tap : tap + 1;
                f = Wk[(oc * IN_C + j) * 9 + tf];
            }
        }
        ws16[idx] = f2bf(f);
    }
}

// ---------------- main kernel helpers ----------------
// x chunk: 32 ic x 4 rows x 64 cols. tasks [r(4)][q(16)][icp(16)] = 1024 = 256*4
__device__ __forceinline__ void stage_x_loads(const float* __restrict__ x, int n, int y0,
                                              int ck, int t, float4 v[4][2]) {
    const int g = ck & 3, h2 = ck >> 2;
    #pragma unroll
    for (int it = 0; it < 4; ++it) {
        int tau = t + it * 256;
        int icp = tau & 15, q = (tau >> 4) & 15, r = tau >> 8;
        int i0 = icp * 2;
        int j0 = g + 4 * (32 * h2 + i0);
        int gy = y0 + r - 1;
        float4 z = {0.f, 0.f, 0.f, 0.f};
        v[it][0] = z; v[it][1] = z;
        if ((unsigned)gy < 64u) {
            const float* p0 = x + (((size_t)n * IN_C + j0) << 12) + (gy << 6) + (q << 2);
            v[it][0] = *(const float4*)p0;
            v[it][1] = *(const float4*)(p0 + 16384);   // plane j0+4 (K elem i0+1)
        }
    }
}

__device__ __forceinline__ void stage_x_writes(int t, float4 v[4][2], unsigned short* __restrict__ xb) {
    #pragma unroll
    for (int it = 0; it < 4; ++it) {
        int tau = t + it * 256;
        int icp = tau & 15, q = (tau >> 4) & 15, r = tau >> 8;
        int i0 = icp * 2;
        unsigned d0 = pkbf(v[it][0].x, v[it][1].x);
        unsigned d1 = pkbf(v[it][0].y, v[it][1].y);
        unsigned d2 = pkbf(v[it][0].z, v[it][1].z);
        unsigned d3 = pkbf(v[it][0].w, v[it][1].w);
        int rb = (r * 66 + q * 4 + 1) * 40 + i0;
        *(unsigned*)&xb[rb]        = d0;
        *(unsigned*)&xb[rb + 40]   = d1;
        *(unsigned*)&xb[rb + 80]   = d2;
        *(unsigned*)&xb[rb + 120]  = d3;
    }
}

// ---------------- main MFMA kernel ----------------
// Block: 256 thr (4 waves, 2 mrow x 2 ncol). Computes all 256 oc x 128 px
// (2 output rows x 64 cols) for one (n, ytile). K-loop: 8 chunks of 32 ic.
__global__ __launch_bounds__(256, 2)
void hetconv_mfma(const float* __restrict__ x,
                  const unsigned short* __restrict__ wsw,
                  float* __restrict__ out) {
    __shared__ unsigned short xs[4 * 66 * 40];   // 21120 B  [r][c 0..65][ic pad40]
    __shared__ unsigned short wh[256 * 40];      // 20480 B  W_hat chunk [p][i pad40]
    __shared__ unsigned short wk[4 * 64 * 40];   // 20480 B  4 taps [tap][lo][i pad40]

    const int t    = threadIdx.x;
    const int l    = t & 63;
    const int w    = t >> 6;
    const int mrow = w & 1;
    const int ncol = w >> 1;
    const int lrow = l & 15;
    const int kc   = l >> 4;

    const int bid = blockIdx.x;                 // 1024 blocks (r2-proven mapping)
    const int n   = (bid & 7) * 4 + (bid >> 8);
    const int y0  = ((bid >> 3) & 31) * 2;

    f32x4 acc[8][4];
    #pragma unroll
    for (int mi = 0; mi < 8; ++mi)
        #pragma unroll
        for (int ni = 0; ni < 4; ++ni) acc[mi][ni] = (f32x4){0.f, 0.f, 0.f, 0.f};

    // ---- prologue: zero halo cols (never re-written) + hoist chunk-0 x loads ----
    if (t < 128) {
        int r = t >> 5, side = (t >> 4) & 1, u = t & 15;
        *(unsigned*)&xs[(r * 66 + side * 65) * 40 + u * 2] = 0u;
    }
    float4 xv[4][2];
    stage_x_loads(x, n, y0, 0, t, xv);

    // ---- 8 chunks, 4 barriers each, loads hoisted one phase ----
#define CHUNK(CK, LAST)                                                             \
    {                                                                               \
        const unsigned short* hs = wsw + (CK) * 10240;                              \
        const unsigned short* ks = wsw + 81920 + (CK) * 20480;                      \
        __syncthreads();                       /* (1) tapsB(prev) done with xs */   \
        bf16x8 wv[10];                                                              \
        _Pragma("unroll")                                                           \
        for (int it = 0; it < 5; ++it) {       /* wh+wka loads first (overlap) */   \
            int e = (t + it * 256) * 8;                                             \
            wv[it]     = *(const bf16x8*)&hs[e];                                    \
            wv[5 + it] = *(const bf16x8*)&ks[e];                                    \
        }                                                                           \
        stage_x_writes(t, xv, xs);             /* cvt_pk + ds_write (covers wv) */  \
        _Pragma("unroll")                                                           \
        for (int it = 0; it < 5; ++it) {                                            \
            int e = (t + it * 256) * 8;                                             \
            *(bf16x8*)&wh[e] = wv[it];                                              \
            *(bf16x8*)&wk[e] = wv[5 + it];                                          \
        }                                                                           \
        __syncthreads();                       /* (2) xs, wh, wka ready */          \
        bf16x8 wvb[5];                                                              \
        _Pragma("unroll")                                                           \
        for (int it = 0; it < 5; ++it)         /* wkb loads (overlap compute) */    \
            wvb[it] = *(const bf16x8*)&ks[10240 + (t + it * 256) * 8];              \
        {   /* part A: dense pointwise, K=32 */                                     \
            bf16x8 a[8], b[4];                                                      \
            _Pragma("unroll")                                                       \
            for (int mi = 0; mi < 8; ++mi) {                                        \
                int m = mrow + 2 * mi;                                              \
                a[mi] = *(const bf16x8*)&wh[(m * 16 + lrow) * 40 + kc * 8];         \
            }                                                                       \
            _Pragma("unroll")                                                       \
            for (int ni = 0; ni < 4; ++ni)                                          \
                b[ni] = *(const bf16x8*)&xs[((ncol + 1) * 66 + ni * 16 + lrow + 1) * 40 + kc * 8]; \
            _Pragma("unroll")                                                       \
            for (int mi = 0; mi < 8; ++mi)                                          \
                _Pragma("unroll")                                                   \
                for (int ni = 0; ni < 4; ++ni)                                      \
                    acc[mi][ni] = __builtin_amdgcn_mfma_f32_16x16x32_bf16(a[mi], b[ni], acc[mi][ni], 0, 0, 0); \
        }                                                                           \
        {   /* part B taps 0-3 (tap_full 0..3) */                                   \
            constexpr int G = (CK) & 3;                                             \
            _Pragma("unroll")                                                       \
            for (int tp = 0; tp < 4; ++tp) {                                        \
                const int dy = tp / 3 - 1, dx = tp % 3 - 1;                         \
                bf16x8 a0 = *(const bf16x8*)&wk[(tp * 64 + mrow * 16 + lrow) * 40 + kc * 8]; \
                bf16x8 a1 = *(const bf16x8*)&wk[(tp * 64 + (mrow + 2) * 16 + lrow) * 40 + kc * 8]; \
                _Pragma("unroll")                                                   \
                for (int ni = 0; ni < 4; ++ni) {                                    \
                    bf16x8 bb = *(const bf16x8*)&xs[((ncol + 1 + dy) * 66 + ni * 16 + lrow + 1 + dx) * 40 + kc * 8]; \
                    acc[2 * G + 0][ni] = __builtin_amdgcn_mfma_f32_16x16x32_bf16(a0, bb, acc[2 * G + 0][ni], 0, 0, 0); \
                    acc[2 * G + 1][ni] = __builtin_amdgcn_mfma_f32_16x16x32_bf16(a1, bb, acc[2 * G + 1][ni], 0, 0, 0); \
                }                                                                   \
            }                                                                       \
        }                                                                           \
        __syncthreads();                       /* (3) wka reads done */             \
        _Pragma("unroll")                                                           \
        for (int it = 0; it < 5; ++it)                                              \
            *(bf16x8*)&wk[(t + it * 256) * 8] = wvb[it];                            \
        if (!(LAST)) stage_x_loads(x, n, y0, (CK) + 1, t, xv);  /* overlap tapsB */ \
        __syncthreads();                       /* (4) wkb ready */                  \
        {   /* part B taps 4-7 (tap_full 5..8) */                                   \
            constexpr int G = (CK) & 3;                                             \
            _Pragma("unroll")                                                       \
            for (int tp = 0; tp < 4; ++tp) {                                        \
                const int tf = tp + 5;                                              \
                const int dy = tf / 3 - 1, dx = tf % 3 - 1;                         \
                bf16x8 a0 = *(const bf16x8*)&wk[(tp * 64 + mrow * 16 + lrow) * 40 + kc * 8]; \
                bf16x8 a1 = *(const bf16x8*)&wk[(tp * 64 + (mrow + 2) * 16 + lrow) * 40 + kc * 8]; \
                _Pragma("unroll")                                                   \
                for (int ni = 0; ni < 4; ++ni) {                                    \
                    bf16x8 bb = *(const bf16x8*)&xs[((ncol + 1 + dy) * 66 + ni * 16 + lrow + 1 + dx) * 40 + kc * 8]; \
                    acc[2 * G + 0][ni] = __builtin_amdgcn_mfma_f32_16x16x32_bf16(a0, bb, acc[2 * G + 0][ni], 0, 0, 0); \
                    acc[2 * G + 1][ni] = __builtin_amdgcn_mfma_f32_16x16x32_bf16(a1, bb, acc[2 * G + 1][ni], 0, 0, 0); \
                }                                                                   \
            }                                                                       \
        }                                                                           \
    }

    CHUNK(0, 0) CHUNK(1, 0) CHUNK(2, 0) CHUNK(3, 0)
    CHUNK(4, 0) CHUNK(5, 0) CHUNK(6, 0) CHUNK(7, 1)
#undef CHUNK

    // ---- epilogue: C/D layout col=lane&15, row=(lane>>4)*4+reg ----
    #pragma unroll
    for (int mi = 0; mi < 8; ++mi) {
        int m = mrow + 2 * mi;
        #pragma unroll
        for (int ni = 0; ni < 4; ++ni) {
            #pragma unroll
            for (int reg = 0; reg < 4; ++reg) {
                int p  = m * 16 + kc * 4 + reg;
                int oc = 4 * (p & 63) + (p >> 6);
                out[(((size_t)n * OUT_C + oc) * HH + (y0 + ncol)) * WW + ni * 16 + lrow] = acc[mi][ni][reg];
            }
        }
    }
}

// ---------------- fp32 fallback (only if ws too small) ----------------
#define TH 16
#define TW 16
#define ICC 16
__global__ __launch_bounds__(256)
void hetconv_fp32(const float* __restrict__ x,
                  const float* __restrict__ Wk,
                  const float* __restrict__ W1,
                  float* __restrict__ out) {
    const int t    = threadIdx.x;
    const int g    = blockIdx.y;
    const int n    = blockIdx.z;
    const int tile = blockIdx.x;
    const int ty0  = (tile >> 2) * TH;
    const int tx0  = (tile & 3) * TW;
    const int ol = t & 7;
    const int pl = t >> 3;
    const int r  = pl >> 1;
    const int ch = (pl & 1) * 8;
    __shared__ __align__(16) float xsf[ICC * 18 * 20];
    __shared__ __align__(16) float w1s[ICC * 64];
    __shared__ __align__(16) float wksf[4 * 9 * 64];
    float acc[8][8];
    #pragma unroll
    for (int k = 0; k < 8; ++k)
        #pragma unroll
        for (int p = 0; p < 8; ++p) acc[k][p] = 0.f;
    for (int ic0 = 0; ic0 < IN_C; ic0 += ICC) {
        for (int idx = t; idx < ICC * 18 * 18; idx += 256) {
            int ic = idx / 324, rem = idx - ic * 324, rr = rem / 18, cc = rem - rr * 18;
            int gy = ty0 + rr - 1, gx = tx0 + cc - 1;
            float v = 0.f;
            if (gy >= 0 && gy < HH && gx >= 0 && gx < WW)
                v = x[(((size_t)n * IN_C + ic0 + ic) * HH + gy) * WW + gx];
            xsf[ic * 360 + rr * 20 + cc] = v;
        }
        for (int idx = t; idx < ICC * 64; idx += 256) {
            int ic = idx >> 6, o = idx & 63;
            w1s[idx] = W1[(g + 4 * o) * IN_C + ic0 + ic];
        }
        for (int idx = t; idx < 4 * 9 * 64; idx += 256) {
            int a = idx / 576, rem = idx - a * 576, tap = rem >> 6, o = rem & 63;
            wksf[idx] = Wk[((g + 4 * o) * IN_C + ic0 + g + 4 * a) * 9 + tap];
        }
        __syncthreads();
        for (int ic = 0; ic < ICC; ++ic) {
            if ((ic & 3) != g) {
                const float* rowp = &xsf[ic * 360 + (r + 1) * 20 + ch];
                float4 A = *(const float4*)rowp;
                float4 B = *(const float4*)(rowp + 4);
                float  c8 = rowp[8];
                float xv2[8] = {A.y, A.z, A.w, B.x, B.y, B.z, B.w, c8};
                const float* wp = &w1s[ic * 64 + ol * 8];
                float4 wA = *(const float4*)wp;
                float4 wB = *(const float4*)(wp + 4);
                float wv2[8] = {wA.x, wA.y, wA.z, wA.w, wB.x, wB.y, wB.z, wB.w};
                #pragma unroll
                for (int k = 0; k < 8; ++k)
                    #pragma unroll
                    for (int p = 0; p < 8; ++p) acc[k][p] += wv2[k] * xv2[p];
            } else {
                const int a = ic >> 2;
                #pragma unroll
                for (int dy = -1; dy <= 1; ++dy) {
                    const float* rowp = &xsf[ic * 360 + (r + 1 + dy) * 20 + ch];
                    float4 A = *(const float4*)rowp;
                    float4 B = *(const float4*)(rowp + 4);
                    float2 C = *(const float2*)(rowp + 8);
                    float seg[10] = {A.x, A.y, A.z, A.w, B.x, B.y, B.z, B.w, C.x, C.y};
                    #pragma unroll
                    for (int dxi = 0; dxi < 3; ++dxi) {
                        const float* wp = &wksf[(a * 9 + (dy + 1) * 3 + dxi) * 64 + ol * 8];
                        float4 wA = *(const float4*)wp;
                        float4 wB = *(const float4*)(wp + 4);
                        float wv2[8] = {wA.x, wA.y, wA.z, wA.w, wB.x, wB.y, wB.z, wB.w};
                        #pragma unroll
                        for (int k = 0; k < 8; ++k)
                            #pragma unroll
                            for (int p = 0; p < 8; ++p) acc[k][p] += wv2[k] * seg[p + dxi];
                    }
                }
            }
        }
        __syncthreads();
    }
    #pragma unroll
    for (int k = 0; k < 8; ++k) {
        int oc = g + 4 * (ol * 8 + k);
        size_t base = (((size_t)n * OUT_C + oc) * HH + (ty0 + r)) * WW + tx0 + ch;
        float4 v0 = {acc[k][0], acc[k][1], acc[k][2], acc[k][3]};
        float4 v1 = {acc[k][4], acc[k][5], acc[k][6], acc[k][7]};
        *(float4*)(&out[base])     = v0;
        *(float4*)(&out[base + 4]) = v1;
    }
}

extern "C" void kernel_launch(void* const* d_in, const int* in_sizes, int n_in,
                              void* d_out, int out_size, void* d_ws, size_t ws_size,
                              hipStream_t stream) {
    const float* x  = (const float*)d_in[0];
    const float* Wk = (const float*)d_in[1];
    const float* W1 = (const float*)d_in[2];
    float* outp = (float*)d_out;

    if (ws_size >= (size_t)(81920 + 163840) * sizeof(unsigned short)) {
        hetconv_prep<<<240, 256, 0, stream>>>(Wk, W1, (unsigned short*)d_ws);
        hetconv_mfma<<<1024, 256, 0, stream>>>(x, (const unsigned short*)d_ws, outp);
    } else {
        hetconv_fp32<<<dim3(16, 4, 32), 256, 0, stream>>>(x, Wk, W1, outp);
    }
}